// Round 11
// baseline (947.961 us; speedup 1.0000x reference)
//
#include <hip/hip_runtime.h>
#include <hip/hip_bf16.h>

// B=16, N=256, P=8, D=512, H=8, E=4096, dh=512, scale=1/8. Outputs fp32.
// Round 11: round-9 gemm skeleton (256^2, BK=64, dbuf, counted vmcnt(8),
// T2 both-sides swizzle, 2 raw barriers/K-tile) with the compute region
// handed to the COMPILER's fine-grained lgkmcnt scheduling (round-10's
// hand-pinned counted lgkmcnt + sched_barrier(0) regressed, per m141/m196).
// setprio(1) wraps the compute region; trailing lgkmcnt(0) guards the
// buffer-swap barrier. convert6 single dispatch (round 10). Attention
// kernels unchanged (validated rounds 5-10).

typedef unsigned short u16;
typedef _Float16 f16;
typedef __attribute__((ext_vector_type(8))) _Float16 v8h;    // 8 f16 = 4 VGPR
typedef __attribute__((ext_vector_type(8))) short vu16x8;    // raw 16B
typedef __attribute__((ext_vector_type(4))) float vf32x4;    // MFMA acc

#define MFMA_F16(a, b, c) __builtin_amdgcn_mfma_f32_16x16x32_f16(a, b, c, 0, 0, 0)

__device__ __forceinline__ void gld16(const void* g, void* l) {
    // async global->LDS, 16B/lane; LDS dest = wave-uniform base + lane*16
    __builtin_amdgcn_global_load_lds((const __attribute__((address_space(1))) void*)g,
                                     (__attribute__((address_space(3))) void*)l,
                                     16, 0, 0);
}

// ---------------- fp32 -> f16, 6 arrays in one dispatch ----------------------
struct Cv6 { const float* s[6]; f16* d[6]; };

__global__ __launch_bounds__(256) void convert6(Cv6 p) {
    const int a = blockIdx.y;
    const size_t i = ((size_t)blockIdx.x * 256 + threadIdx.x) * 4;
    const float4 v = *(const float4*)(p.s[a] + i);
    f16* d = p.d[a] + i;
    d[0] = (f16)v.x; d[1] = (f16)v.y; d[2] = (f16)v.z; d[3] = (f16)v.w;
}

// ---------------- 256^2 pipelined f16 NT GEMM: C = A@B^T + bias (+pos) ------
// 512 thr = 8 waves (2M x 4N), per-wave 128x64 out = 8x4 frags. BK=64.
// MODE 0: +bias +pos -> f16 ; MODE 1: +bias -> f16 ; MODE 2: +bias -> fp32.
template <int MODE>
__global__ __launch_bounds__(512, 2)
void gemm8_nt(const f16* __restrict__ A, const f16* __restrict__ Bw,
              const float* __restrict__ bias, const float* __restrict__ pos,
              f16* __restrict__ Ch, float* __restrict__ Cf) {
    __shared__ __align__(16) u16 sA[2][16384];   // 256 rows x 64 f16, swizzled
    __shared__ __align__(16) u16 sB[2][16384];
    const int t = threadIdx.x;
    const int lane = t & 63, w = t >> 6;
    const int wm = w >> 2, wn = w & 3;           // 2 x 4 wave grid
    const int l15 = lane & 15, lg = lane >> 4;
    // XCD-chunked block swizzle (256 blocks, 32 per XCD = 2 tile-rows)
    const int wg = ((blockIdx.x & 7) << 5) + (blockIdx.x >> 3);
    const int m0 = (wg >> 4) << 8, n0 = (wg & 15) << 8;

    // staging: LDS chunk c (16B) holds global (row=c>>3, colchunk=(c&7)^(row&7))
    int srow[4], scol[4];
#pragma unroll
    for (int i = 0; i < 4; ++i) {
        const int c = t + (i << 9);
        srow[i] = c >> 3;
        scol[i] = (((c & 7) ^ (srow[i] & 7)) << 3);    // f16-element offset
    }
    // ds_read bases
    const int rA = (wm << 7) + l15;              // A row (within 256)
    const int rB = (wn << 6) + l15;              // B row (within 256)
    const int xA = rA & 7, xB = rB & 7;          // swizzle keys (row&7)
    const int ccA0 = ((0 + lg) ^ xA) << 3;       // kk=0 swizzled col (f16 units)
    const int ccA1 = ((4 + lg) ^ xA) << 3;       // kk=1
    const int ccB0 = ((0 + lg) ^ xB) << 3;
    const int ccB1 = ((4 + lg) ^ xB) << 3;

    vf32x4 acc[8][4] = {};

#define STAGE(buf, k0) do {                                                    \
    _Pragma("unroll")                                                          \
    for (int i = 0; i < 4; ++i) {                                              \
        const int c = t + (i << 9);                                            \
        gld16(A  + (((size_t)(m0 + srow[i])) << 12) + (k0) + scol[i],          \
              &sA[buf][c * 8]);                                                \
    }                                                                          \
    _Pragma("unroll")                                                          \
    for (int i = 0; i < 4; ++i) {                                              \
        const int c = t + (i << 9);                                            \
        gld16(Bw + (((size_t)(n0 + srow[i])) << 12) + (k0) + scol[i],          \
              &sB[buf][c * 8]);                                                \
    }                                                                          \
} while (0)

    STAGE(0, 0);                                 // prologue: tile 0

    for (int kt = 0; kt < 64; ++kt) {
        const int cb = kt & 1;
        if (kt < 63) {
            STAGE(cb ^ 1, (kt + 1) << 6);        // issue t+1 BEFORE the wait
            asm volatile("s_waitcnt vmcnt(8)" ::: "memory");  // tile t landed
        } else {
            asm volatile("s_waitcnt vmcnt(0)" ::: "memory");
        }
        __builtin_amdgcn_s_barrier();            // all waves' tile-t loads in
        __builtin_amdgcn_s_setprio(1);
        // Compute region: plain LDS loads + MFMAs, NO asm waits/pins inside.
        // The compiler emits fine-grained counted lgkmcnt between each
        // ds_read and its first consuming MFMA (m97 evidence) and is free to
        // overlap kk1 reads with kk0 MFMAs.
        {
            v8h av[8], bv[4];
#pragma unroll
            for (int n = 0; n < 4; ++n)
                bv[n] = *(const v8h*)(&sB[cb][(rB << 6) + (n << 10) + ccB0]);
#pragma unroll
            for (int m = 0; m < 8; ++m)
                av[m] = *(const v8h*)(&sA[cb][(rA << 6) + (m << 10) + ccA0]);
#pragma unroll
            for (int m = 0; m < 8; ++m)
#pragma unroll
                for (int n = 0; n < 4; ++n)
                    acc[m][n] = MFMA_F16(av[m], bv[n], acc[m][n]);
        }
        {
            v8h av[8], bv[4];
#pragma unroll
            for (int n = 0; n < 4; ++n)
                bv[n] = *(const v8h*)(&sB[cb][(rB << 6) + (n << 10) + ccB1]);
#pragma unroll
            for (int m = 0; m < 8; ++m)
                av[m] = *(const v8h*)(&sA[cb][(rA << 6) + (m << 10) + ccA1]);
#pragma unroll
            for (int m = 0; m < 8; ++m)
#pragma unroll
                for (int n = 0; n < 4; ++n)
                    acc[m][n] = MFMA_F16(av[m], bv[n], acc[m][n]);
        }
        __builtin_amdgcn_s_setprio(0);
        // All ds_reads were consumed above (compiler waits enforced); this
        // drain is post-MFMA (~free) and guards the next tile's LDS writes.
        asm volatile("s_waitcnt lgkmcnt(0)" ::: "memory");
        __builtin_amdgcn_s_barrier();            // block done reading buf cb
    }
#undef STAGE

#pragma unroll
    for (int n = 0; n < 4; ++n) {
        const int col = n0 + (wn << 6) + (n << 4) + l15;
        const float bvv = bias[col];
#pragma unroll
        for (int m = 0; m < 8; ++m) {
#pragma unroll
            for (int r = 0; r < 4; ++r) {
                const int row = m0 + (wm << 7) + (m << 4) + (lg << 2) + r;
                float v = acc[m][n][r] + bvv;
                if (MODE == 0) v += pos[((size_t)(row & 255) << 12) + col];
                if (MODE == 2)
                    Cf[((size_t)row << 12) + col] = v;
                else
                    Ch[((size_t)row << 12) + col] = (f16)v;
            }
        }
    }
}

// ---------------- f16 scores + softmax -> P fp32 (out1) + P f16 (PV) --------
// grid = 128 (b,h) * 4 q-slabs of 64 rows; block computes 64x256 scores.
__global__ __launch_bounds__(256)
void attn_scores(const f16* __restrict__ q, const f16* __restrict__ k,
                 float* __restrict__ Pf, f16* __restrict__ Pb) {
    const int blk = blockIdx.x;
    const int bh = blk >> 2, it = blk & 3;
    const int b = bh >> 3, h = bh & 7;
    const size_t qoff = ((size_t)(b * 256 + it * 64) << 12) + (h << 9);
    const size_t koff = ((size_t)(b * 256) << 12) + (h << 9);
    __shared__ __align__(16) u16 Qs[64 * 64];
    __shared__ __align__(16) u16 Ks[256 * 64];
    __shared__ float red[4][64];

    const int t = threadIdx.x;
    const int lane = t & 63, w = t >> 6;
    const int l15 = lane & 15, lg = lane >> 4;

    vf32x4 acc[4][4] = {};

    for (int k0 = 0; k0 < 512; k0 += 64) {
#pragma unroll
        for (int i = 0; i < 2; ++i) {               // Q slab: 64x64
            const int c = t + (i << 8);
            const int row = c >> 3, c8 = (c & 7) << 3;
            gld16(q + qoff + ((size_t)row << 12) + k0 + c8, Qs + c * 8);
        }
#pragma unroll
        for (int i = 0; i < 8; ++i) {               // K: 256x64
            const int c = t + (i << 8);
            const int row = c >> 3, c8 = (c & 7) << 3;
            gld16(k + koff + ((size_t)row << 12) + k0 + c8, Ks + c * 8);
        }
        __syncthreads();
#pragma unroll
        for (int kk = 0; kk < 2; ++kk) {
            v8h af[4], bf[4];
#pragma unroll
            for (int m = 0; m < 4; ++m)
                af[m] = *(const v8h*)(Qs + (m * 16 + l15) * 64 + kk * 32 + lg * 8);
#pragma unroll
            for (int n = 0; n < 4; ++n)
                bf[n] = *(const v8h*)(Ks + (w * 64 + n * 16 + l15) * 64 + kk * 32 + lg * 8);
#pragma unroll
            for (int m = 0; m < 4; ++m)
#pragma unroll
                for (int n = 0; n < 4; ++n)
                    acc[m][n] = MFMA_F16(af[m], bf[n], acc[m][n]);
        }
        __syncthreads();
    }

#pragma unroll
    for (int m = 0; m < 4; ++m)
#pragma unroll
        for (int n = 0; n < 4; ++n) acc[m][n] *= 0.125f;

    // row max: lane-local over n, shfl over 16-lane col group, LDS over waves
    float gm[4][4];
#pragma unroll
    for (int m = 0; m < 4; ++m)
#pragma unroll
        for (int r = 0; r < 4; ++r) {
            float v = fmaxf(fmaxf(acc[m][0][r], acc[m][1][r]),
                            fmaxf(acc[m][2][r], acc[m][3][r]));
#pragma unroll
            for (int off = 1; off < 16; off <<= 1) v = fmaxf(v, __shfl_xor(v, off));
            gm[m][r] = v;
        }
    if (l15 == 0) {
#pragma unroll
        for (int m = 0; m < 4; ++m)
#pragma unroll
            for (int r = 0; r < 4; ++r) red[w][m * 16 + lg * 4 + r] = gm[m][r];
    }
    __syncthreads();
#pragma unroll
    for (int m = 0; m < 4; ++m)
#pragma unroll
        for (int r = 0; r < 4; ++r) {
            const int row = m * 16 + lg * 4 + r;
            gm[m][r] = fmaxf(fmaxf(red[0][row], red[1][row]),
                             fmaxf(red[2][row], red[3][row]));
        }
    __syncthreads();   // protect red reuse

    // exp + row sum
    float gs[4][4];
#pragma unroll
    for (int m = 0; m < 4; ++m)
#pragma unroll
        for (int r = 0; r < 4; ++r) {
            float s = 0.f;
#pragma unroll
            for (int n = 0; n < 4; ++n) {
                const float e = __expf(acc[m][n][r] - gm[m][r]);
                acc[m][n][r] = e;
                s += e;
            }
#pragma unroll
            for (int off = 1; off < 16; off <<= 1) s += __shfl_xor(s, off);
            gs[m][r] = s;
        }
    if (l15 == 0) {
#pragma unroll
        for (int m = 0; m < 4; ++m)
#pragma unroll
            for (int r = 0; r < 4; ++r) red[w][m * 16 + lg * 4 + r] = gs[m][r];
    }
    __syncthreads();

    const size_t pbase = ((size_t)bh * 256 + it * 64) * 256;
#pragma unroll
    for (int m = 0; m < 4; ++m)
#pragma unroll
        for (int r = 0; r < 4; ++r) {
            const int row = m * 16 + lg * 4 + r;
            const float inv = 1.0f / (red[0][row] + red[1][row] +
                                      red[2][row] + red[3][row]);
#pragma unroll
            for (int n = 0; n < 4; ++n) {
                const int col = w * 64 + n * 16 + l15;
                const float p = acc[m][n][r] * inv;
                Pf[pbase + (size_t)row * 256 + col] = p;
                Pb[pbase + (size_t)row * 256 + col] = (f16)p;
            }
        }
}

// ---------------- PV: ao[b,n,h*512+j] = sum_m P[b,h,n,m] * v[b,m,h*512+j] ---
// grid = 128 bh * 2 m-tiles * 4 n-tiles; 128x128 tile; V staged transposed.
__global__ __launch_bounds__(256)
void attn_pv(const f16* __restrict__ P, const f16* __restrict__ V,
             f16* __restrict__ O) {
    __shared__ __align__(16) u16 Ps[128 * 64];
    __shared__ __align__(16) u16 Vt[128 * 72];   // [j][m], padded stride 72
    const int t = threadIdx.x;
    const int lane = t & 63, w = t >> 6;
    const int wr = (w >> 1) << 6, wc = (w & 1) << 6;
    const int l15 = lane & 15, lg = lane >> 4;
    const int blk = blockIdx.x;
    const int bh = blk >> 3, mt = (blk >> 2) & 1, nt = blk & 3;
    const int b = bh >> 3, h = bh & 7;
    const f16* Pbp = P + ((size_t)bh << 16) + ((size_t)mt << 15);
    const u16* Vb = (const u16*)V + ((size_t)(b * 256) << 12) + (h << 9) + (nt << 7);

    vf32x4 acc[4][4] = {};

    for (int k0 = 0; k0 < 256; k0 += 64) {
#pragma unroll
        for (int i = 0; i < 4; ++i) {               // P tile 128x64, linear
            const int c = t + (i << 8);
            const int row = c >> 3, c8 = (c & 7) << 3;
            gld16(Pbp + (size_t)row * 256 + k0 + c8, Ps + c * 8);
        }
#pragma unroll
        for (int pp = 0; pp < 4; ++pp) {            // V tile 64x128, transposed
            const int kr = pp * 16 + (t >> 4);
            const int c8 = (t & 15) << 3;
            vu16x8 vv = *(const vu16x8*)(Vb + ((size_t)(k0 + kr) << 12) + c8);
#pragma unroll
            for (int c = 0; c < 8; ++c) Vt[(c8 + c) * 72 + kr] = (u16)vv[c];
        }
        __syncthreads();
#pragma unroll
        for (int kk = 0; kk < 2; ++kk) {
            v8h af[4], bf[4];
#pragma unroll
            for (int m = 0; m < 4; ++m)
                af[m] = *(const v8h*)(Ps + (wr + m * 16 + l15) * 64 + kk * 32 + lg * 8);
#pragma unroll
            for (int n = 0; n < 4; ++n)
                bf[n] = *(const v8h*)(Vt + (wc + n * 16 + l15) * 72 + kk * 32 + lg * 8);
#pragma unroll
            for (int m = 0; m < 4; ++m)
#pragma unroll
                for (int n = 0; n < 4; ++n)
                    acc[m][n] = MFMA_F16(af[m], bf[n], acc[m][n]);
        }
        __syncthreads();
    }

#pragma unroll
    for (int m = 0; m < 4; ++m)
#pragma unroll
        for (int n = 0; n < 4; ++n) {
            const int col = (h << 9) + (nt << 7) + wc + n * 16 + l15;
#pragma unroll
            for (int r = 0; r < 4; ++r) {
                const int row = b * 256 + mt * 128 + wr + m * 16 + lg * 4 + r;
                O[((size_t)row << 12) + col] = (f16)acc[m][n][r];
            }
        }
}

// ---------------------------------------------------------------------------
extern "C" void kernel_launch(void* const* d_in, const int* in_sizes, int n_in,
                              void* d_out, int out_size, void* d_ws, size_t ws_size,
                              hipStream_t stream) {
    const float* x   = (const float*)d_in[0];
    const float* pos = (const float*)d_in[1];
    const float* wE  = (const float*)d_in[2];
    const float* bE  = (const float*)d_in[3];
    const float* wQ  = (const float*)d_in[4];
    const float* bq  = (const float*)d_in[5];
    const float* wK  = (const float*)d_in[6];
    const float* bk  = (const float*)d_in[7];
    const float* wV  = (const float*)d_in[8];
    const float* bv  = (const float*)d_in[9];
    const float* wO  = (const float*)d_in[10];
    const float* bo  = (const float*)d_in[11];

    float* out  = (float*)d_out;                    // output 0: 16,777,216 fp32
    float* Pout = out + (size_t)16777216;           // output 1:  8,388,608 fp32

    // ws layout (MiB offsets), peak 288 MiB (proven available, round 1)
    char* W = (char*)d_ws;
    const size_t MB = 1024 * 1024;
    f16* xf  = (f16*)(W + 0 * MB);       // x f16; later ao (x dead post-embed)
    f16* xe  = (f16*)(W + 32 * MB);      // embedded activations f16
    f16* ks  = (f16*)(W + 64 * MB);      // K f16
    f16* vs  = (f16*)(W + 96 * MB);      // V f16
    f16* wEs = (f16*)(W + 128 * MB);
    f16* wQs = (f16*)(W + 160 * MB);
    f16* wKs = (f16*)(W + 192 * MB);
    f16* wVs = (f16*)(W + 224 * MB);
    f16* wOs = (f16*)(W + 256 * MB);
    f16* ao  = xf;
    // d_out scratch (dead before final GEMM overwrites out0):
    f16* qs  = (f16*)out;                // 32 MiB (out0 bytes 0-32Mi)
    f16* Pb  = (f16*)(out + (size_t)8388608);   // 16 MiB (out0 bytes 32-48Mi)

    Cv6 cv;
    cv.s[0] = x;  cv.d[0] = xf;
    cv.s[1] = wE; cv.d[1] = wEs;
    cv.s[2] = wQ; cv.d[2] = wQs;
    cv.s[3] = wK; cv.d[3] = wKs;
    cv.s[4] = wV; cv.d[4] = wVs;
    cv.s[5] = wO; cv.d[5] = wOs;
    convert6<<<dim3(16384, 6), 256, 0, stream>>>(cv);

    gemm8_nt<0><<<256, 512, 0, stream>>>(xf, wEs, bE, pos, xe, nullptr);
    gemm8_nt<1><<<256, 512, 0, stream>>>(xe, wQs, bq, nullptr, qs, nullptr);
    gemm8_nt<1><<<256, 512, 0, stream>>>(xe, wKs, bk, nullptr, ks, nullptr);
    gemm8_nt<1><<<256, 512, 0, stream>>>(xe, wVs, bv, nullptr, vs, nullptr);

    attn_scores<<<512, 256, 0, stream>>>(qs, ks, Pout, Pb);
    attn_pv<<<1024, 256, 0, stream>>>(Pb, vs, ao);

    gemm8_nt<2><<<256, 512, 0, stream>>>(ao, wOs, bo, nullptr, nullptr, out);
}

// Round 12
// 942.677 us; speedup vs baseline: 1.0056x; 1.0056x over previous
//
#include <hip/hip_runtime.h>
#include <hip/hip_bf16.h>

// B=16, N=256, P=8, D=512, H=8, E=4096, dh=512, scale=1/8. Outputs fp32.
// Round 12: consolidation. gemm8 inner loop reverted EXACTLY to round 9's
// schedule (read 12 -> lgkmcnt(0) -> 32-MFMA cluster, per kk) which measured
// 167us/34% vs round 10's pinned sub-phases (190us) and round 11's
// compiler-free (198us). Keeps from rounds 10/11: convert6 single dispatch,
// d_out scratch for q/P-f16, ws 288 MiB layout. Attention unchanged.

typedef unsigned short u16;
typedef _Float16 f16;
typedef __attribute__((ext_vector_type(8))) _Float16 v8h;    // 8 f16 = 4 VGPR
typedef __attribute__((ext_vector_type(8))) short vu16x8;    // raw 16B
typedef __attribute__((ext_vector_type(4))) float vf32x4;    // MFMA acc

#define MFMA_F16(a, b, c) __builtin_amdgcn_mfma_f32_16x16x32_f16(a, b, c, 0, 0, 0)

__device__ __forceinline__ void gld16(const void* g, void* l) {
    // async global->LDS, 16B/lane; LDS dest = wave-uniform base + lane*16
    __builtin_amdgcn_global_load_lds((const __attribute__((address_space(1))) void*)g,
                                     (__attribute__((address_space(3))) void*)l,
                                     16, 0, 0);
}

// ---------------- fp32 -> f16, 6 arrays in one dispatch ----------------------
struct Cv6 { const float* s[6]; f16* d[6]; };

__global__ __launch_bounds__(256) void convert6(Cv6 p) {
    const int a = blockIdx.y;
    const size_t i = ((size_t)blockIdx.x * 256 + threadIdx.x) * 4;
    const float4 v = *(const float4*)(p.s[a] + i);
    f16* d = p.d[a] + i;
    d[0] = (f16)v.x; d[1] = (f16)v.y; d[2] = (f16)v.z; d[3] = (f16)v.w;
}

// ---------------- 256^2 pipelined f16 NT GEMM: C = A@B^T + bias (+pos) ------
// 512 thr = 8 waves (2M x 4N), per-wave 128x64 out = 8x4 frags. BK=64.
// MODE 0: +bias +pos -> f16 ; MODE 1: +bias -> f16 ; MODE 2: +bias -> fp32.
template <int MODE>
__global__ __launch_bounds__(512, 2)
void gemm8_nt(const f16* __restrict__ A, const f16* __restrict__ Bw,
              const float* __restrict__ bias, const float* __restrict__ pos,
              f16* __restrict__ Ch, float* __restrict__ Cf) {
    __shared__ __align__(16) u16 sA[2][16384];   // 256 rows x 64 f16, swizzled
    __shared__ __align__(16) u16 sB[2][16384];
    const int t = threadIdx.x;
    const int lane = t & 63, w = t >> 6;
    const int wm = w >> 2, wn = w & 3;           // 2 x 4 wave grid
    const int l15 = lane & 15, lg = lane >> 4;
    // XCD-chunked block swizzle (256 blocks, 32 per XCD = 2 tile-rows)
    const int wg = ((blockIdx.x & 7) << 5) + (blockIdx.x >> 3);
    const int m0 = (wg >> 4) << 8, n0 = (wg & 15) << 8;

    // staging: LDS chunk c (16B) holds global (row=c>>3, colchunk=(c&7)^(row&7))
    int srow[4], scol[4];
#pragma unroll
    for (int i = 0; i < 4; ++i) {
        const int c = t + (i << 9);
        srow[i] = c >> 3;
        scol[i] = (((c & 7) ^ (srow[i] & 7)) << 3);    // f16-element offset
    }
    // ds_read bases
    const int rA = (wm << 7) + l15;              // A row (within 256)
    const int rB = (wn << 6) + l15;              // B row (within 256)
    const int xA = rA & 7, xB = rB & 7;          // swizzle keys (row&7)

    vf32x4 acc[8][4] = {};

#define STAGE(buf, k0) do {                                                    \
    _Pragma("unroll")                                                          \
    for (int i = 0; i < 4; ++i) {                                              \
        const int c = t + (i << 9);                                            \
        gld16(A  + (((size_t)(m0 + srow[i])) << 12) + (k0) + scol[i],          \
              &sA[buf][c * 8]);                                                \
    }                                                                          \
    _Pragma("unroll")                                                          \
    for (int i = 0; i < 4; ++i) {                                              \
        const int c = t + (i << 9);                                            \
        gld16(Bw + (((size_t)(n0 + srow[i])) << 12) + (k0) + scol[i],          \
              &sB[buf][c * 8]);                                                \
    }                                                                          \
} while (0)

    STAGE(0, 0);                                 // prologue: tile 0

    for (int kt = 0; kt < 64; ++kt) {
        const int cb = kt & 1;
        if (kt < 63) {
            STAGE(cb ^ 1, (kt + 1) << 6);        // issue t+1 BEFORE the wait
            asm volatile("s_waitcnt vmcnt(8)" ::: "memory");  // tile t landed
        } else {
            asm volatile("s_waitcnt vmcnt(0)" ::: "memory");
        }
        __builtin_amdgcn_s_barrier();            // all waves' tile-t loads in
        asm volatile("" ::: "memory");
#pragma unroll
        for (int kk = 0; kk < 2; ++kk) {
            const int ccA = (((kk << 2) + lg) ^ xA) << 3;   // swizzled col (f16)
            const int ccB = (((kk << 2) + lg) ^ xB) << 3;
            v8h av[8], bv[4];
#pragma unroll
            for (int m = 0; m < 8; ++m)
                av[m] = *(const v8h*)(&sA[cb][(rA << 6) + (m << 10) + ccA]);
#pragma unroll
            for (int n = 0; n < 4; ++n)
                bv[n] = *(const v8h*)(&sB[cb][(rB << 6) + (n << 10) + ccB]);
            asm volatile("s_waitcnt lgkmcnt(0)" ::: "memory");
            __builtin_amdgcn_sched_barrier(0);
            __builtin_amdgcn_s_setprio(1);
#pragma unroll
            for (int m = 0; m < 8; ++m)
#pragma unroll
                for (int n = 0; n < 4; ++n)
                    acc[m][n] = MFMA_F16(av[m], bv[n], acc[m][n]);
            __builtin_amdgcn_s_setprio(0);
        }
        __builtin_amdgcn_s_barrier();            // tile-t reads done before any
        asm volatile("" ::: "memory");           // t+2 load lands in buf[cb]
    }
#undef STAGE

#pragma unroll
    for (int n = 0; n < 4; ++n) {
        const int col = n0 + (wn << 6) + (n << 4) + l15;
        const float bvv = bias[col];
#pragma unroll
        for (int m = 0; m < 8; ++m) {
#pragma unroll
            for (int r = 0; r < 4; ++r) {
                const int row = m0 + (wm << 7) + (m << 4) + (lg << 2) + r;
                float v = acc[m][n][r] + bvv;
                if (MODE == 0) v += pos[((size_t)(row & 255) << 12) + col];
                if (MODE == 2)
                    Cf[((size_t)row << 12) + col] = v;
                else
                    Ch[((size_t)row << 12) + col] = (f16)v;
            }
        }
    }
}

// ---------------- f16 scores + softmax -> P fp32 (out1) + P f16 (PV) --------
// grid = 128 (b,h) * 4 q-slabs of 64 rows; block computes 64x256 scores.
__global__ __launch_bounds__(256)
void attn_scores(const f16* __restrict__ q, const f16* __restrict__ k,
                 float* __restrict__ Pf, f16* __restrict__ Pb) {
    const int blk = blockIdx.x;
    const int bh = blk >> 2, it = blk & 3;
    const int b = bh >> 3, h = bh & 7;
    const size_t qoff = ((size_t)(b * 256 + it * 64) << 12) + (h << 9);
    const size_t koff = ((size_t)(b * 256) << 12) + (h << 9);
    __shared__ __align__(16) u16 Qs[64 * 64];
    __shared__ __align__(16) u16 Ks[256 * 64];
    __shared__ float red[4][64];

    const int t = threadIdx.x;
    const int lane = t & 63, w = t >> 6;
    const int l15 = lane & 15, lg = lane >> 4;

    vf32x4 acc[4][4] = {};

    for (int k0 = 0; k0 < 512; k0 += 64) {
#pragma unroll
        for (int i = 0; i < 2; ++i) {               // Q slab: 64x64
            const int c = t + (i << 8);
            const int row = c >> 3, c8 = (c & 7) << 3;
            gld16(q + qoff + ((size_t)row << 12) + k0 + c8, Qs + c * 8);
        }
#pragma unroll
        for (int i = 0; i < 8; ++i) {               // K: 256x64
            const int c = t + (i << 8);
            const int row = c >> 3, c8 = (c & 7) << 3;
            gld16(k + koff + ((size_t)row << 12) + k0 + c8, Ks + c * 8);
        }
        __syncthreads();
#pragma unroll
        for (int kk = 0; kk < 2; ++kk) {
            v8h af[4], bf[4];
#pragma unroll
            for (int m = 0; m < 4; ++m)
                af[m] = *(const v8h*)(Qs + (m * 16 + l15) * 64 + kk * 32 + lg * 8);
#pragma unroll
            for (int n = 0; n < 4; ++n)
                bf[n] = *(const v8h*)(Ks + (w * 64 + n * 16 + l15) * 64 + kk * 32 + lg * 8);
#pragma unroll
            for (int m = 0; m < 4; ++m)
#pragma unroll
                for (int n = 0; n < 4; ++n)
                    acc[m][n] = MFMA_F16(af[m], bf[n], acc[m][n]);
        }
        __syncthreads();
    }

#pragma unroll
    for (int m = 0; m < 4; ++m)
#pragma unroll
        for (int n = 0; n < 4; ++n) acc[m][n] *= 0.125f;

    // row max: lane-local over n, shfl over 16-lane col group, LDS over waves
    float gm[4][4];
#pragma unroll
    for (int m = 0; m < 4; ++m)
#pragma unroll
        for (int r = 0; r < 4; ++r) {
            float v = fmaxf(fmaxf(acc[m][0][r], acc[m][1][r]),
                            fmaxf(acc[m][2][r], acc[m][3][r]));
#pragma unroll
            for (int off = 1; off < 16; off <<= 1) v = fmaxf(v, __shfl_xor(v, off));
            gm[m][r] = v;
        }
    if (l15 == 0) {
#pragma unroll
        for (int m = 0; m < 4; ++m)
#pragma unroll
            for (int r = 0; r < 4; ++r) red[w][m * 16 + lg * 4 + r] = gm[m][r];
    }
    __syncthreads();
#pragma unroll
    for (int m = 0; m < 4; ++m)
#pragma unroll
        for (int r = 0; r < 4; ++r) {
            const int row = m * 16 + lg * 4 + r;
            gm[m][r] = fmaxf(fmaxf(red[0][row], red[1][row]),
                             fmaxf(red[2][row], red[3][row]));
        }
    __syncthreads();   // protect red reuse

    // exp + row sum
    float gs[4][4];
#pragma unroll
    for (int m = 0; m < 4; ++m)
#pragma unroll
        for (int r = 0; r < 4; ++r) {
            float s = 0.f;
#pragma unroll
            for (int n = 0; n < 4; ++n) {
                const float e = __expf(acc[m][n][r] - gm[m][r]);
                acc[m][n][r] = e;
                s += e;
            }
#pragma unroll
            for (int off = 1; off < 16; off <<= 1) s += __shfl_xor(s, off);
            gs[m][r] = s;
        }
    if (l15 == 0) {
#pragma unroll
        for (int m = 0; m < 4; ++m)
#pragma unroll
            for (int r = 0; r < 4; ++r) red[w][m * 16 + lg * 4 + r] = gs[m][r];
    }
    __syncthreads();

    const size_t pbase = ((size_t)bh * 256 + it * 64) * 256;
#pragma unroll
    for (int m = 0; m < 4; ++m)
#pragma unroll
        for (int r = 0; r < 4; ++r) {
            const int row = m * 16 + lg * 4 + r;
            const float inv = 1.0f / (red[0][row] + red[1][row] +
                                      red[2][row] + red[3][row]);
#pragma unroll
            for (int n = 0; n < 4; ++n) {
                const int col = w * 64 + n * 16 + l15;
                const float p = acc[m][n][r] * inv;
                Pf[pbase + (size_t)row * 256 + col] = p;
                Pb[pbase + (size_t)row * 256 + col] = (f16)p;
            }
        }
}

// ---------------- PV: ao[b,n,h*512+j] = sum_m P[b,h,n,m] * v[b,m,h*512+j] ---
// grid = 128 bh * 2 m-tiles * 4 n-tiles; 128x128 tile; V staged transposed.
__global__ __launch_bounds__(256)
void attn_pv(const f16* __restrict__ P, const f16* __restrict__ V,
             f16* __restrict__ O) {
    __shared__ __align__(16) u16 Ps[128 * 64];
    __shared__ __align__(16) u16 Vt[128 * 72];   // [j][m], padded stride 72
    const int t = threadIdx.x;
    const int lane = t & 63, w = t >> 6;
    const int wr = (w >> 1) << 6, wc = (w & 1) << 6;
    const int l15 = lane & 15, lg = lane >> 4;
    const int blk = blockIdx.x;
    const int bh = blk >> 3, mt = (blk >> 2) & 1, nt = blk & 3;
    const int b = bh >> 3, h = bh & 7;
    const f16* Pbp = P + ((size_t)bh << 16) + ((size_t)mt << 15);
    const u16* Vb = (const u16*)V + ((size_t)(b * 256) << 12) + (h << 9) + (nt << 7);

    vf32x4 acc[4][4] = {};

    for (int k0 = 0; k0 < 256; k0 += 64) {
#pragma unroll
        for (int i = 0; i < 4; ++i) {               // P tile 128x64, linear
            const int c = t + (i << 8);
            const int row = c >> 3, c8 = (c & 7) << 3;
            gld16(Pbp + (size_t)row * 256 + k0 + c8, Ps + c * 8);
        }
#pragma unroll
        for (int pp = 0; pp < 4; ++pp) {            // V tile 64x128, transposed
            const int kr = pp * 16 + (t >> 4);
            const int c8 = (t & 15) << 3;
            vu16x8 vv = *(const vu16x8*)(Vb + ((size_t)(k0 + kr) << 12) + c8);
#pragma unroll
            for (int c = 0; c < 8; ++c) Vt[(c8 + c) * 72 + kr] = (u16)vv[c];
        }
        __syncthreads();
#pragma unroll
        for (int kk = 0; kk < 2; ++kk) {
            v8h af[4], bf[4];
#pragma unroll
            for (int m = 0; m < 4; ++m)
                af[m] = *(const v8h*)(Ps + (wr + m * 16 + l15) * 64 + kk * 32 + lg * 8);
#pragma unroll
            for (int n = 0; n < 4; ++n)
                bf[n] = *(const v8h*)(Vt + (wc + n * 16 + l15) * 72 + kk * 32 + lg * 8);
#pragma unroll
            for (int m = 0; m < 4; ++m)
#pragma unroll
                for (int n = 0; n < 4; ++n)
                    acc[m][n] = MFMA_F16(af[m], bf[n], acc[m][n]);
        }
        __syncthreads();
    }

#pragma unroll
    for (int m = 0; m < 4; ++m)
#pragma unroll
        for (int n = 0; n < 4; ++n) {
            const int col = (h << 9) + (nt << 7) + wc + n * 16 + l15;
#pragma unroll
            for (int r = 0; r < 4; ++r) {
                const int row = b * 256 + mt * 128 + wr + m * 16 + lg * 4 + r;
                O[((size_t)row << 12) + col] = (f16)acc[m][n][r];
            }
        }
}

// ---------------------------------------------------------------------------
extern "C" void kernel_launch(void* const* d_in, const int* in_sizes, int n_in,
                              void* d_out, int out_size, void* d_ws, size_t ws_size,
                              hipStream_t stream) {
    const float* x   = (const float*)d_in[0];
    const float* pos = (const float*)d_in[1];
    const float* wE  = (const float*)d_in[2];
    const float* bE  = (const float*)d_in[3];
    const float* wQ  = (const float*)d_in[4];
    const float* bq  = (const float*)d_in[5];
    const float* wK  = (const float*)d_in[6];
    const float* bk  = (const float*)d_in[7];
    const float* wV  = (const float*)d_in[8];
    const float* bv  = (const float*)d_in[9];
    const float* wO  = (const float*)d_in[10];
    const float* bo  = (const float*)d_in[11];

    float* out  = (float*)d_out;                    // output 0: 16,777,216 fp32
    float* Pout = out + (size_t)16777216;           // output 1:  8,388,608 fp32

    // ws layout (MiB offsets), peak 288 MiB (proven available, round 1)
    char* W = (char*)d_ws;
    const size_t MB = 1024 * 1024;
    f16* xf  = (f16*)(W + 0 * MB);       // x f16; later ao (x dead post-embed)
    f16* xe  = (f16*)(W + 32 * MB);      // embedded activations f16
    f16* ks  = (f16*)(W + 64 * MB);      // K f16
    f16* vs  = (f16*)(W + 96 * MB);      // V f16
    f16* wEs = (f16*)(W + 128 * MB);
    f16* wQs = (f16*)(W + 160 * MB);
    f16* wKs = (f16*)(W + 192 * MB);
    f16* wVs = (f16*)(W + 224 * MB);
    f16* wOs = (f16*)(W + 256 * MB);
    f16* ao  = xf;
    // d_out scratch (dead before final GEMM overwrites out0):
    f16* qs  = (f16*)out;                // 32 MiB (out0 bytes 0-32Mi)
    f16* Pb  = (f16*)(out + (size_t)8388608);   // 16 MiB (out0 bytes 32-48Mi)

    Cv6 cv;
    cv.s[0] = x;  cv.d[0] = xf;
    cv.s[1] = wE; cv.d[1] = wEs;
    cv.s[2] = wQ; cv.d[2] = wQs;
    cv.s[3] = wK; cv.d[3] = wKs;
    cv.s[4] = wV; cv.d[4] = wVs;
    cv.s[5] = wO; cv.d[5] = wOs;
    convert6<<<dim3(16384, 6), 256, 0, stream>>>(cv);

    gemm8_nt<0><<<256, 512, 0, stream>>>(xf, wEs, bE, pos, xe, nullptr);
    gemm8_nt<1><<<256, 512, 0, stream>>>(xe, wQs, bq, nullptr, qs, nullptr);
    gemm8_nt<1><<<256, 512, 0, stream>>>(xe, wKs, bk, nullptr, ks, nullptr);
    gemm8_nt<1><<<256, 512, 0, stream>>>(xe, wVs, bv, nullptr, vs, nullptr);

    attn_scores<<<512, 256, 0, stream>>>(qs, ks, Pout, Pb);
    attn_pv<<<1024, 256, 0, stream>>>(Pb, vs, ao);

    gemm8_nt<2><<<256, 512, 0, stream>>>(ao, wOs, bo, nullptr, nullptr, out);
}

// Round 13
// 859.045 us; speedup vs baseline: 1.1035x; 1.0974x over previous
//
#include <hip/hip_runtime.h>
#include <hip/hip_bf16.h>

// B=16, N=256, P=8, D=512, H=8, E=4096, dh=512, scale=1/8. Outputs fp32.
// Round 13: restore round 9's measured-best configuration EXACTLY (the
// round-10 "consolidation" regressed ~25us/gemm: batching all converts up
// front evicted GEMM operands from L3; interleaved per-GEMM converts keep
// them hot -- FETCH unchanged, fetch RATE 1.3->0.9 TB/s was the tell).
// Only new change: XCD-contiguous block swizzle in attn kernels (blocks
// sharing a (b,h)'s K/V land on one XCD's L2). GEMM kernel = round 9/12
// source (schedule A/B'd across rounds 9-12: read-12/drain/32-MFMA wins).

typedef unsigned short u16;
typedef _Float16 f16;
typedef __attribute__((ext_vector_type(8))) _Float16 v8h;    // 8 f16 = 4 VGPR
typedef __attribute__((ext_vector_type(8))) short vu16x8;    // raw 16B
typedef __attribute__((ext_vector_type(4))) float vf32x4;    // MFMA acc

#define MFMA_F16(a, b, c) __builtin_amdgcn_mfma_f32_16x16x32_f16(a, b, c, 0, 0, 0)

__device__ __forceinline__ void gld16(const void* g, void* l) {
    // async global->LDS, 16B/lane; LDS dest = wave-uniform base + lane*16
    __builtin_amdgcn_global_load_lds((const __attribute__((address_space(1))) void*)g,
                                     (__attribute__((address_space(3))) void*)l,
                                     16, 0, 0);
}

// ---------------- fp32 -> f16 ------------------------------------------------
__global__ __launch_bounds__(256) void tof16(const float* __restrict__ s,
                                             f16* __restrict__ d) {
    const size_t i = ((size_t)blockIdx.x * 256 + threadIdx.x) * 4;
    const float4 v = *(const float4*)(s + i);
    d[i + 0] = (f16)v.x; d[i + 1] = (f16)v.y;
    d[i + 2] = (f16)v.z; d[i + 3] = (f16)v.w;
}

// ---------------- 256^2 pipelined f16 NT GEMM: C = A@B^T + bias (+pos) ------
// 512 thr = 8 waves (2M x 4N), per-wave 128x64 out = 8x4 frags. BK=64.
// MODE 0: +bias +pos -> f16 ; MODE 1: +bias -> f16 ; MODE 2: +bias -> fp32.
template <int MODE>
__global__ __launch_bounds__(512, 2)
void gemm8_nt(const f16* __restrict__ A, const f16* __restrict__ Bw,
              const float* __restrict__ bias, const float* __restrict__ pos,
              f16* __restrict__ Ch, float* __restrict__ Cf) {
    __shared__ __align__(16) u16 sA[2][16384];   // 256 rows x 64 f16, swizzled
    __shared__ __align__(16) u16 sB[2][16384];
    const int t = threadIdx.x;
    const int lane = t & 63, w = t >> 6;
    const int wm = w >> 2, wn = w & 3;           // 2 x 4 wave grid
    const int l15 = lane & 15, lg = lane >> 4;
    // XCD-chunked block swizzle (256 blocks, 32 per XCD = 2 tile-rows)
    const int wg = ((blockIdx.x & 7) << 5) + (blockIdx.x >> 3);
    const int m0 = (wg >> 4) << 8, n0 = (wg & 15) << 8;

    // staging: LDS chunk c (16B) holds global (row=c>>3, colchunk=(c&7)^(row&7))
    int srow[4], scol[4];
#pragma unroll
    for (int i = 0; i < 4; ++i) {
        const int c = t + (i << 9);
        srow[i] = c >> 3;
        scol[i] = (((c & 7) ^ (srow[i] & 7)) << 3);    // f16-element offset
    }
    // ds_read bases
    const int rA = (wm << 7) + l15;              // A row (within 256)
    const int rB = (wn << 6) + l15;              // B row (within 256)
    const int xA = rA & 7, xB = rB & 7;          // swizzle keys (row&7)

    vf32x4 acc[8][4] = {};

#define STAGE(buf, k0) do {                                                    \
    _Pragma("unroll")                                                          \
    for (int i = 0; i < 4; ++i) {                                              \
        const int c = t + (i << 9);                                            \
        gld16(A  + (((size_t)(m0 + srow[i])) << 12) + (k0) + scol[i],          \
              &sA[buf][c * 8]);                                                \
    }                                                                          \
    _Pragma("unroll")                                                          \
    for (int i = 0; i < 4; ++i) {                                              \
        const int c = t + (i << 9);                                            \
        gld16(Bw + (((size_t)(n0 + srow[i])) << 12) + (k0) + scol[i],          \
              &sB[buf][c * 8]);                                                \
    }                                                                          \
} while (0)

    STAGE(0, 0);                                 // prologue: tile 0

    for (int kt = 0; kt < 64; ++kt) {
        const int cb = kt & 1;
        if (kt < 63) {
            STAGE(cb ^ 1, (kt + 1) << 6);        // issue t+1 BEFORE the wait
            asm volatile("s_waitcnt vmcnt(8)" ::: "memory");  // tile t landed
        } else {
            asm volatile("s_waitcnt vmcnt(0)" ::: "memory");
        }
        __builtin_amdgcn_s_barrier();            // all waves' tile-t loads in
        asm volatile("" ::: "memory");
#pragma unroll
        for (int kk = 0; kk < 2; ++kk) {
            const int ccA = (((kk << 2) + lg) ^ xA) << 3;   // swizzled col (f16)
            const int ccB = (((kk << 2) + lg) ^ xB) << 3;
            v8h av[8], bv[4];
#pragma unroll
            for (int m = 0; m < 8; ++m)
                av[m] = *(const v8h*)(&sA[cb][(rA << 6) + (m << 10) + ccA]);
#pragma unroll
            for (int n = 0; n < 4; ++n)
                bv[n] = *(const v8h*)(&sB[cb][(rB << 6) + (n << 10) + ccB]);
            asm volatile("s_waitcnt lgkmcnt(0)" ::: "memory");
            __builtin_amdgcn_sched_barrier(0);
            __builtin_amdgcn_s_setprio(1);
#pragma unroll
            for (int m = 0; m < 8; ++m)
#pragma unroll
                for (int n = 0; n < 4; ++n)
                    acc[m][n] = MFMA_F16(av[m], bv[n], acc[m][n]);
            __builtin_amdgcn_s_setprio(0);
        }
        __builtin_amdgcn_s_barrier();            // tile-t reads done before any
        asm volatile("" ::: "memory");           // t+2 load lands in buf[cb]
    }
#undef STAGE

#pragma unroll
    for (int n = 0; n < 4; ++n) {
        const int col = n0 + (wn << 6) + (n << 4) + l15;
        const float bvv = bias[col];
#pragma unroll
        for (int m = 0; m < 8; ++m) {
#pragma unroll
            for (int r = 0; r < 4; ++r) {
                const int row = m0 + (wm << 7) + (m << 4) + (lg << 2) + r;
                float v = acc[m][n][r] + bvv;
                if (MODE == 0) v += pos[((size_t)(row & 255) << 12) + col];
                if (MODE == 2)
                    Cf[((size_t)row << 12) + col] = v;
                else
                    Ch[((size_t)row << 12) + col] = (f16)v;
            }
        }
    }
}

// ---------------- f16 scores + softmax -> P fp32 (out1) + P f16 (PV) --------
// grid = 512: XCD-contiguous remap so the 4 q-slab blocks of one (b,h)
// share an XCD's L2 (they all read the same K panel).
__global__ __launch_bounds__(256)
void attn_scores(const f16* __restrict__ q, const f16* __restrict__ k,
                 float* __restrict__ Pf, f16* __restrict__ Pb) {
    const int blk = ((blockIdx.x & 7) << 6) + (blockIdx.x >> 3);  // 8 XCDs x 64
    const int bh = blk >> 2, it = blk & 3;
    const int b = bh >> 3, h = bh & 7;
    const size_t qoff = ((size_t)(b * 256 + it * 64) << 12) + (h << 9);
    const size_t koff = ((size_t)(b * 256) << 12) + (h << 9);
    __shared__ __align__(16) u16 Qs[64 * 64];
    __shared__ __align__(16) u16 Ks[256 * 64];
    __shared__ float red[4][64];

    const int t = threadIdx.x;
    const int lane = t & 63, w = t >> 6;
    const int l15 = lane & 15, lg = lane >> 4;

    vf32x4 acc[4][4] = {};

    for (int k0 = 0; k0 < 512; k0 += 64) {
#pragma unroll
        for (int i = 0; i < 2; ++i) {               // Q slab: 64x64
            const int c = t + (i << 8);
            const int row = c >> 3, c8 = (c & 7) << 3;
            gld16(q + qoff + ((size_t)row << 12) + k0 + c8, Qs + c * 8);
        }
#pragma unroll
        for (int i = 0; i < 8; ++i) {               // K: 256x64
            const int c = t + (i << 8);
            const int row = c >> 3, c8 = (c & 7) << 3;
            gld16(k + koff + ((size_t)row << 12) + k0 + c8, Ks + c * 8);
        }
        __syncthreads();
#pragma unroll
        for (int kk = 0; kk < 2; ++kk) {
            v8h af[4], bf[4];
#pragma unroll
            for (int m = 0; m < 4; ++m)
                af[m] = *(const v8h*)(Qs + (m * 16 + l15) * 64 + kk * 32 + lg * 8);
#pragma unroll
            for (int n = 0; n < 4; ++n)
                bf[n] = *(const v8h*)(Ks + (w * 64 + n * 16 + l15) * 64 + kk * 32 + lg * 8);
#pragma unroll
            for (int m = 0; m < 4; ++m)
#pragma unroll
                for (int n = 0; n < 4; ++n)
                    acc[m][n] = MFMA_F16(af[m], bf[n], acc[m][n]);
        }
        __syncthreads();
    }

#pragma unroll
    for (int m = 0; m < 4; ++m)
#pragma unroll
        for (int n = 0; n < 4; ++n) acc[m][n] *= 0.125f;

    // row max: lane-local over n, shfl over 16-lane col group, LDS over waves
    float gm[4][4];
#pragma unroll
    for (int m = 0; m < 4; ++m)
#pragma unroll
        for (int r = 0; r < 4; ++r) {
            float v = fmaxf(fmaxf(acc[m][0][r], acc[m][1][r]),
                            fmaxf(acc[m][2][r], acc[m][3][r]));
#pragma unroll
            for (int off = 1; off < 16; off <<= 1) v = fmaxf(v, __shfl_xor(v, off));
            gm[m][r] = v;
        }
    if (l15 == 0) {
#pragma unroll
        for (int m = 0; m < 4; ++m)
#pragma unroll
            for (int r = 0; r < 4; ++r) red[w][m * 16 + lg * 4 + r] = gm[m][r];
    }
    __syncthreads();
#pragma unroll
    for (int m = 0; m < 4; ++m)
#pragma unroll
        for (int r = 0; r < 4; ++r) {
            const int row = m * 16 + lg * 4 + r;
            gm[m][r] = fmaxf(fmaxf(red[0][row], red[1][row]),
                             fmaxf(red[2][row], red[3][row]));
        }
    __syncthreads();   // protect red reuse

    // exp + row sum
    float gs[4][4];
#pragma unroll
    for (int m = 0; m < 4; ++m)
#pragma unroll
        for (int r = 0; r < 4; ++r) {
            float s = 0.f;
#pragma unroll
            for (int n = 0; n < 4; ++n) {
                const float e = __expf(acc[m][n][r] - gm[m][r]);
                acc[m][n][r] = e;
                s += e;
            }
#pragma unroll
            for (int off = 1; off < 16; off <<= 1) s += __shfl_xor(s, off);
            gs[m][r] = s;
        }
    if (l15 == 0) {
#pragma unroll
        for (int m = 0; m < 4; ++m)
#pragma unroll
            for (int r = 0; r < 4; ++r) red[w][m * 16 + lg * 4 + r] = gs[m][r];
    }
    __syncthreads();

    const size_t pbase = ((size_t)bh * 256 + it * 64) * 256;
#pragma unroll
    for (int m = 0; m < 4; ++m)
#pragma unroll
        for (int r = 0; r < 4; ++r) {
            const int row = m * 16 + lg * 4 + r;
            const float inv = 1.0f / (red[0][row] + red[1][row] +
                                      red[2][row] + red[3][row]);
#pragma unroll
            for (int n = 0; n < 4; ++n) {
                const int col = w * 64 + n * 16 + l15;
                const float p = acc[m][n][r] * inv;
                Pf[pbase + (size_t)row * 256 + col] = p;
                Pb[pbase + (size_t)row * 256 + col] = (f16)p;
            }
        }
}

// ---------------- PV: ao[b,n,h*512+j] = sum_m P[b,h,n,m] * v[b,m,h*512+j] ---
// grid = 1024: XCD-contiguous remap (8 blocks of one (b,h) share V in L2).
__global__ __launch_bounds__(256)
void attn_pv(const f16* __restrict__ P, const f16* __restrict__ V,
             f16* __restrict__ O) {
    __shared__ __align__(16) u16 Ps[128 * 64];
    __shared__ __align__(16) u16 Vt[128 * 72];   // [j][m], padded stride 72
    const int t = threadIdx.x;
    const int lane = t & 63, w = t >> 6;
    const int wr = (w >> 1) << 6, wc = (w & 1) << 6;
    const int l15 = lane & 15, lg = lane >> 4;
    const int blk = ((blockIdx.x & 7) << 7) + (blockIdx.x >> 3);  // 8 x 128
    const int bh = blk >> 3, mt = (blk >> 2) & 1, nt = blk & 3;
    const int b = bh >> 3, h = bh & 7;
    const f16* Pbp = P + ((size_t)bh << 16) + ((size_t)mt << 15);
    const u16* Vb = (const u16*)V + ((size_t)(b * 256) << 12) + (h << 9) + (nt << 7);

    vf32x4 acc[4][4] = {};

    for (int k0 = 0; k0 < 256; k0 += 64) {
#pragma unroll
        for (int i = 0; i < 4; ++i) {               // P tile 128x64, linear
            const int c = t + (i << 8);
            const int row = c >> 3, c8 = (c & 7) << 3;
            gld16(Pbp + (size_t)row * 256 + k0 + c8, Ps + c * 8);
        }
#pragma unroll
        for (int pp = 0; pp < 4; ++pp) {            // V tile 64x128, transposed
            const int kr = pp * 16 + (t >> 4);
            const int c8 = (t & 15) << 3;
            vu16x8 vv = *(const vu16x8*)(Vb + ((size_t)(k0 + kr) << 12) + c8);
#pragma unroll
            for (int c = 0; c < 8; ++c) Vt[(c8 + c) * 72 + kr] = (u16)vv[c];
        }
        __syncthreads();
#pragma unroll
        for (int kk = 0; kk < 2; ++kk) {
            v8h af[4], bf[4];
#pragma unroll
            for (int m = 0; m < 4; ++m)
                af[m] = *(const v8h*)(Ps + (wr + m * 16 + l15) * 64 + kk * 32 + lg * 8);
#pragma unroll
            for (int n = 0; n < 4; ++n)
                bf[n] = *(const v8h*)(Vt + (wc + n * 16 + l15) * 72 + kk * 32 + lg * 8);
#pragma unroll
            for (int m = 0; m < 4; ++m)
#pragma unroll
                for (int n = 0; n < 4; ++n)
                    acc[m][n] = MFMA_F16(af[m], bf[n], acc[m][n]);
        }
        __syncthreads();
    }

#pragma unroll
    for (int m = 0; m < 4; ++m)
#pragma unroll
        for (int n = 0; n < 4; ++n) {
            const int col = (h << 9) + (nt << 7) + wc + n * 16 + l15;
#pragma unroll
            for (int r = 0; r < 4; ++r) {
                const int row = b * 256 + mt * 128 + wr + m * 16 + lg * 4 + r;
                O[((size_t)row << 12) + col] = (f16)acc[m][n][r];
            }
        }
}

// ---------------------------------------------------------------------------
extern "C" void kernel_launch(void* const* d_in, const int* in_sizes, int n_in,
                              void* d_out, int out_size, void* d_ws, size_t ws_size,
                              hipStream_t stream) {
    const float* x   = (const float*)d_in[0];
    const float* pos = (const float*)d_in[1];
    const float* wE  = (const float*)d_in[2];
    const float* bE  = (const float*)d_in[3];
    const float* wQ  = (const float*)d_in[4];
    const float* bq  = (const float*)d_in[5];
    const float* wK  = (const float*)d_in[6];
    const float* bk  = (const float*)d_in[7];
    const float* wV  = (const float*)d_in[8];
    const float* bv  = (const float*)d_in[9];
    const float* wO  = (const float*)d_in[10];
    const float* bo  = (const float*)d_in[11];

    float* out  = (float*)d_out;                    // output 0: 16,777,216 fp32
    float* Pout = out + (size_t)16777216;           // output 1:  8,388,608 fp32

    // ws layout (MiB offsets), peak 208 MiB — round 9's exact layout
    char* W = (char*)d_ws;
    const size_t MB = 1024 * 1024;
    f16* xf    = (f16*)(W + 0 * MB);     // x f16; later ao (x dead post-embed)
    f16* wslab = (f16*)(W + 32 * MB);    // current weight f16
    f16* xe    = (f16*)(W + 64 * MB);    // embedded activations f16
    f16* qs    = (f16*)(W + 96 * MB);    // Q f16
    f16* ks    = (f16*)(W + 128 * MB);   // K f16
    f16* vs    = (f16*)(W + 160 * MB);   // V f16
    f16* Pb    = (f16*)(W + 192 * MB);   // P f16 (16 MiB)
    f16* ao    = xf;                     // PV result over x (dead)

    const int CVG = 16384;   // 16.7M elems / (256 thr * 4/thread)

    tof16<<<CVG, 256, 0, stream>>>(x, xf);
    tof16<<<CVG, 256, 0, stream>>>(wE, wslab);
    gemm8_nt<0><<<256, 512, 0, stream>>>(xf, wslab, bE, pos, xe, nullptr);

    tof16<<<CVG, 256, 0, stream>>>(wQ, wslab);
    gemm8_nt<1><<<256, 512, 0, stream>>>(xe, wslab, bq, nullptr, qs, nullptr);

    tof16<<<CVG, 256, 0, stream>>>(wK, wslab);
    gemm8_nt<1><<<256, 512, 0, stream>>>(xe, wslab, bk, nullptr, ks, nullptr);

    tof16<<<CVG, 256, 0, stream>>>(wV, wslab);
    gemm8_nt<1><<<256, 512, 0, stream>>>(xe, wslab, bv, nullptr, vs, nullptr);

    attn_scores<<<512, 256, 0, stream>>>(qs, ks, Pout, Pb);
    attn_pv<<<1024, 256, 0, stream>>>(Pb, vs, ao);

    tof16<<<CVG, 256, 0, stream>>>(wO, wslab);
    gemm8_nt<2><<<256, 512, 0, stream>>>(ao, wslab, bo, nullptr, nullptr, out);
}